// Round 1
// 1066.078 us; speedup vs baseline: 67.9940x; 67.9940x over previous
//
#include <hip/hip_runtime.h>

typedef __attribute__((ext_vector_type(8))) unsigned short us8;
typedef __attribute__((ext_vector_type(8))) __bf16 bf16x8;
typedef __attribute__((ext_vector_type(4))) float f32x4;

#define DP  26      // padded plane dim
#define CIP 40      // padded K-slot stride in LDS (shorts)
#define WELEMS 165888   // 3*64*32*27 weight elements (one bf16 plane)

// Reference semantics (derived from xp.reshape(B*D0p, Ci, ...) WITHOUT transpose):
//   out[b,o,d0,d1,d2,d3] = bias[o] + sum_{i<3, c<32, k1,k2,k3}
//       X(b, r=(d0+i)*32+c ; d1+k1-1, d2+k2-1, d3+k3-1) * w[i,o,c,k1,k2,k3]
//   where X(b, r; ...) reads x[b, ci=r/26, pf=r%26-1, ...], zero if pf not in [0,24)
//   or any spatial index out of [0,24).
//
// fp32-exactness strategy (replaces the exhaustive heal pass, which was 99.8% of
// runtime due to accv[64] scratch spill): split-bf16 3-term MFMA.
//   x = hi(x)+lo(x), w = hi(w)+lo(w)   (hi,lo both bf16, lo = rn(f - f32(hi)))
//   acc += Ahi*Bhi + Ahi*Blo + Alo*Bhi  (fp32 MFMA accumulate)
// dropped lo*lo term ~ 2^-18 relative per product -> absmax ~1e-4.

__device__ __forceinline__ unsigned short f2bf(float f) {
    unsigned int u = __builtin_bit_cast(unsigned int, f);
    u += 0x7FFFu + ((u >> 16) & 1u);
    return (unsigned short)(u >> 16);
}

__device__ __forceinline__ void f2bf2(float f, unsigned short& h, unsigned short& l) {
    h = f2bf(f);
    float hf = __builtin_bit_cast(float, (unsigned int)h << 16);
    l = f2bf(f - hf);   // exact fp32 subtract (hi within 2x of f), then round
}

// w: (3,64,32,3,3,3) fp32  ->  w2 bf16 [i][k1][k2][k3][o][c], hi plane + lo plane
__global__ void wconv_kernel(const float* __restrict__ w, unsigned short* __restrict__ w2) {
    int e   = blockIdx.x * 256 + threadIdx.x;   // 648*256 = 165888 exact
    int ci  = e & 31;
    int o   = (e >> 5) & 63;
    int tap = e >> 11;
    int k3 = tap % 3;
    int k2 = (tap / 3) % 3;
    int k1 = (tap / 9) % 3;
    int i  = tap / 27;
    int src = ((i * 64 + o) * 32 + ci) * 27 + (k1 * 9 + k2 * 3 + k3);
    unsigned short h, l;
    f2bf2(w[src], h, l);
    w2[e]          = h;
    w2[e + WELEMS] = l;
}

__global__ __launch_bounds__(256, 1)
void conv4d_kernel(const float* __restrict__ x, const unsigned short* __restrict__ w2,
                   const float* __restrict__ bias, float* __restrict__ out) {
    __shared__ __align__(16) unsigned short xsh[DP * DP * CIP];  // 54,080 B (hi)
    __shared__ __align__(16) unsigned short xsl[DP * DP * CIP];  // 54,080 B (lo)
    __shared__ __align__(16) float tb[4][320];                   //  5,120 B

    const int tid  = threadIdx.x;
    const int lane = tid & 63;
    const int wv   = tid >> 6;
    const int n    = lane & 15;
    const int q    = lane >> 4;

    const int bid = blockIdx.x;
    const int d1 = bid % 24;
    const int d0 = (bid / 24) % 24;
    const int b  = bid / 576;

    for (int e = tid; e < DP * DP * CIP; e += 256) { xsh[e] = 0; xsl[e] = 0; }

    int abase[9];
    #pragma unroll
    for (int t = 0; t < 9; ++t) {
        int mflat = (wv * 9 + t) * 16 + n;
        int d2o = mflat / 24;
        int d3o = mflat - d2o * 24;
        abase[t] = (d2o * DP + d3o) * CIP + q * 8;
    }

    f32x4 acc[9][4];
    #pragma unroll
    for (int t = 0; t < 9; ++t)
        #pragma unroll
        for (int nt = 0; nt < 4; ++nt)
            acc[t][nt] = (f32x4)0.0f;

    const float* xb_b = x + (size_t)b * 10616832;

    for (int i = 0; i < 3; ++i) {                 // NO d0-skip: f=d0+i always valid
        const int rbase = (d0 + i) * 32;
        for (int k1 = 0; k1 < 3; ++k1) {
            int d1in = d1 + k1 - 1;
            if (d1in < 0 || d1in >= 24) continue; // spatial pad, block-uniform

            __syncthreads();
            {
                const float* xb = xb_b + (size_t)d1in * 576;
                for (int cc = tid; cc < 4608; cc += 256) {
                    int d3c = cc % 6;
                    int d2  = (cc / 6) % 24;
                    int c   = cc / 144;            // K slot = weight channel
                    int r   = rbase + c;
                    int ci  = r / 26;
                    int pf  = r - ci * 26 - 1;     // source frame, may be pad
                    float4 v = make_float4(0.f, 0.f, 0.f, 0.f);
                    if (pf >= 0 && pf < 24)
                        v = *(const float4*)(xb + (size_t)ci * 331776 + pf * 13824 + d2 * 24 + d3c * 4);
                    int le = ((d2 + 1) * DP + (d3c * 4 + 1)) * CIP + c;
                    unsigned short h, l;
                    f2bf2(v.x, h, l); xsh[le]           = h; xsl[le]           = l;
                    f2bf2(v.y, h, l); xsh[le + CIP]     = h; xsl[le + CIP]     = l;
                    f2bf2(v.z, h, l); xsh[le + 2 * CIP] = h; xsl[le + 2 * CIP] = l;
                    f2bf2(v.w, h, l); xsh[le + 3 * CIP] = h; xsl[le + 3 * CIP] = l;
                }
            }
            __syncthreads();

            const unsigned short* wsliceH = w2 + (size_t)((i * 3 + k1) * 9) * 2048;
            const unsigned short* wsliceL = wsliceH + WELEMS;
            #pragma unroll
            for (int k2 = 0; k2 < 3; ++k2) {
                #pragma unroll
                for (int k3 = 0; k3 < 3; ++k3) {
                    const int tap = k2 * 3 + k3;
                    bf16x8 bh[4], bl[4];
                    #pragma unroll
                    for (int nt = 0; nt < 4; ++nt) {
                        const int wo = (tap * 64 + nt * 16 + n) * 32 + q * 8;
                        bh[nt] = __builtin_bit_cast(bf16x8, *(const us8*)(wsliceH + wo));
                        bl[nt] = __builtin_bit_cast(bf16x8, *(const us8*)(wsliceL + wo));
                    }
                    const int toff = (k2 * DP + k3) * CIP;
                    #pragma unroll
                    for (int t = 0; t < 9; ++t) {
                        const bf16x8 ah = __builtin_bit_cast(bf16x8, *(const us8*)(&xsh[abase[t] + toff]));
                        const bf16x8 al = __builtin_bit_cast(bf16x8, *(const us8*)(&xsl[abase[t] + toff]));
                        #pragma unroll
                        for (int nt = 0; nt < 4; ++nt) {
                            acc[t][nt] = __builtin_amdgcn_mfma_f32_16x16x32_bf16(ah, bh[nt], acc[t][nt], 0, 0, 0);
                            acc[t][nt] = __builtin_amdgcn_mfma_f32_16x16x32_bf16(ah, bl[nt], acc[t][nt], 0, 0, 0);
                            acc[t][nt] = __builtin_amdgcn_mfma_f32_16x16x32_bf16(al, bh[nt], acc[t][nt], 0, 0, 0);
                        }
                    }
                }
            }
        }
    }

    // epilogue, interp A (col=o, row=m — certified by round-2 on-device probes)
    const int o4 = lane >> 2;
    const int mc = lane & 3;
    float* tbw = tb[wv];
    const size_t plane = (size_t)d0 * 24 + d1;
    #pragma unroll
    for (int t = 0; t < 9; ++t) {
        #pragma unroll
        for (int nt = 0; nt < 4; ++nt) {
            __syncthreads();
            *(f32x4*)&tbw[n * 20 + q * 4] = acc[t][nt];   // tb[o=n][m=q*4+r]
            __syncthreads();
            f32x4 v = *(const f32x4*)&tbw[o4 * 20 + mc * 4];
            const int o = nt * 16 + o4;
            v += bias[o];
            size_t off = ((size_t)(b * 64 + o) * 576 + plane) * 576
                       + (size_t)((wv * 9 + t) * 16 + mc * 4);
            *(f32x4*)(out + off) = v;
        }
    }
}

extern "C" void kernel_launch(void* const* d_in, const int* in_sizes, int n_in,
                              void* d_out, int out_size, void* d_ws, size_t ws_size,
                              hipStream_t stream) {
    const float* x    = (const float*)d_in[0];
    const float* w    = (const float*)d_in[1];
    const float* bias = (const float*)d_in[2];
    float* out        = (float*)d_out;
    unsigned short* w2 = (unsigned short*)d_ws;   // hi plane + lo plane = 663,552 B

    hipLaunchKernelGGL(wconv_kernel, dim3(648), dim3(256), 0, stream, w, w2);
    hipLaunchKernelGGL(conv4d_kernel, dim3(2 * 24 * 24), dim3(256), 0, stream,
                       x, w2, bias, out);
}